// Round 1
// baseline (187.065 us; speedup 1.0000x reference)
//
#include <hip/hip_runtime.h>
#include <math.h>

#define N_SAMPLES 524288
#define A_ACT 8
#define D_DIM 64
#define E_DIM 32
#define LOG2PI_F 1.8378770664093453f

#define SORT_THREADS 256
#define CHUNK 4096
#define NBLK (N_SAMPLES / CHUNK)      // 128
#define HIST_SIZE (A_ACT * NBLK)      // 1024
#define SCAN_PER (HIST_SIZE / 256)    // 4

// ---------------- Kernel 1: per-block histogram ----------------
__global__ __launch_bounds__(SORT_THREADS) void hist_kernel(
    const int* __restrict__ idx, int* __restrict__ hist) {
  __shared__ int cnt[A_ACT];
  int t = threadIdx.x;
  if (t < A_ACT) cnt[t] = 0;
  __syncthreads();
  int base = blockIdx.x * CHUNK;
  for (int j = t; j < CHUNK; j += SORT_THREADS) {
    atomicAdd(&cnt[idx[base + j]], 1);
  }
  __syncthreads();
  if (t < A_ACT) hist[t * NBLK + blockIdx.x] = cnt[t];
}

// ---------------- Kernel 2: exclusive scan of hist (1 block) ----------------
__global__ __launch_bounds__(256) void scan_kernel(int* __restrict__ hist) {
  __shared__ int sums[256];
  int t = threadIdx.x;
  int vals[SCAN_PER];
  int s = 0;
#pragma unroll
  for (int k = 0; k < SCAN_PER; ++k) {
    vals[k] = hist[t * SCAN_PER + k];
    s += vals[k];
  }
  sums[t] = s;
  __syncthreads();
  // Hillis-Steele inclusive scan
  for (int off = 1; off < 256; off <<= 1) {
    int v = (t >= off) ? sums[t - off] : 0;
    __syncthreads();
    sums[t] += v;
    __syncthreads();
  }
  int prefix = (t == 0) ? 0 : sums[t - 1];
#pragma unroll
  for (int k = 0; k < SCAN_PER; ++k) {
    int v = vals[k];
    hist[t * SCAN_PER + k] = prefix;
    prefix += v;
  }
}

// ---------------- Kernel 3: stable scatter (builds p and inv) ----------------
__global__ __launch_bounds__(SORT_THREADS) void scatter_kernel(
    const int* __restrict__ idx, const int* __restrict__ offs,
    int* __restrict__ p, int* __restrict__ inv) {
  __shared__ int base[A_ACT];
  __shared__ int wcnt[4][A_ACT];
  int t = threadIdx.x;
  int wave = t >> 6;
  int lane = t & 63;
  if (t < A_ACT) base[t] = offs[t * NBLK + blockIdx.x];
  __syncthreads();
  int cstart = blockIdx.x * CHUNK;
  for (int pass = 0; pass < CHUNK / SORT_THREADS; ++pass) {
    int i = cstart + pass * SORT_THREADS + t;
    int a = idx[i];
    unsigned long long mymask = 0ULL;
#pragma unroll
    for (int aa = 0; aa < A_ACT; ++aa) {
      unsigned long long m = __ballot(a == aa);
      if (aa == a) mymask = m;
      if (lane == 0) wcnt[wave][aa] = __popcll(m);
    }
    unsigned long long below = (1ULL << lane) - 1ULL;
    int inwave = __popcll(mymask & below);
    __syncthreads();
    int wprefix = 0;
#pragma unroll
    for (int w = 0; w < 4; ++w)
      if (w < wave) wprefix += wcnt[w][a];
    int r = base[a] + wprefix + inwave;
    p[r] = i;
    inv[i] = r;
    __syncthreads();
    if (t < A_ACT) {
      int tot = 0;
#pragma unroll
      for (int w = 0; w < 4; ++w) tot += wcnt[w][t];
      base[t] += tot;
    }
    __syncthreads();
  }
}

// ---------------- Kernel 4: fused matvec + rsample + logprob ----------------
#define ROWS_PER_BLOCK 8
__global__ __launch_bounds__(256) void main_kernel(
    const float* __restrict__ state, const float* __restrict__ W,
    const float* __restrict__ b, const float* __restrict__ ls,
    const float* __restrict__ eps, const int* __restrict__ idx,
    const int* __restrict__ p, const int* __restrict__ inv,
    float* __restrict__ out_action, float* __restrict__ out_lp) {
  __shared__ float s_state[ROWS_PER_BLOCK][D_DIM];
  int t = threadIdx.x;
  int wave = t >> 6;
  int lane = t & 63;
  int half = lane >> 5;   // which of the wave's 2 rows
  int e = lane & 31;      // action dim

  int k0 = blockIdx.x * ROWS_PER_BLOCK;
  int kA = k0 + 2 * wave;      // sorted position, half 0
  int kB = kA + 1;             // sorted position, half 1

  int mA = p[kA];
  int mB = p[kB];
  // stage the two state rows (coalesced 256B each)
  s_state[2 * wave + 0][lane] = state[mA * D_DIM + lane];
  s_state[2 * wave + 1][lane] = state[mB * D_DIM + lane];

  int krow = half ? kB : kA;
  int m = half ? mB : mA;
  int a = idx[m];
  int dest = inv[krow];
  float epsv = eps[krow * E_DIM + e];          // coalesced (kB = kA+1)
  float bv = b[a * E_DIM + e];
  float lsv = ls[a * E_DIM + e];

  __syncthreads();

  const float* srow = s_state[2 * wave + half];
  const float* wcol = W + a * (D_DIM * E_DIM) + e;
  float mean = 0.f;
#pragma unroll
  for (int d = 0; d < D_DIM; ++d) {
    mean = fmaf(srow[d], wcol[d * E_DIM], mean);
  }
  mean += bv;
  float stdv = expf(lsv);
  float action = mean + stdv * epsv;
  out_action[(size_t)dest * E_DIM + e] = action;

  // lp = sum_e(-0.5*eps^2 - ls) - 16*log(2pi), reduce over the 32-lane half
  float part = -0.5f * epsv * epsv - lsv;
#pragma unroll
  for (int off = 1; off < 32; off <<= 1) {
    part += __shfl_xor(part, off, 64);
  }
  if (e == 0) out_lp[dest] = part - 16.0f * LOG2PI_F;
}

extern "C" void kernel_launch(void* const* d_in, const int* in_sizes, int n_in,
                              void* d_out, int out_size, void* d_ws, size_t ws_size,
                              hipStream_t stream) {
  const float* state = (const float*)d_in[0];
  const float* W     = (const float*)d_in[1];
  const float* b     = (const float*)d_in[2];
  const float* ls    = (const float*)d_in[3];
  const float* eps   = (const float*)d_in[4];
  const int*   idx   = (const int*)d_in[5];

  float* out_action = (float*)d_out;                       // [N, E]
  float* out_lp     = (float*)d_out + (size_t)N_SAMPLES * E_DIM;  // [N]

  int* p    = (int*)d_ws;
  int* inv  = p + N_SAMPLES;
  int* hist = inv + N_SAMPLES;

  hipLaunchKernelGGL(hist_kernel, dim3(NBLK), dim3(SORT_THREADS), 0, stream,
                     idx, hist);
  hipLaunchKernelGGL(scan_kernel, dim3(1), dim3(256), 0, stream, hist);
  hipLaunchKernelGGL(scatter_kernel, dim3(NBLK), dim3(SORT_THREADS), 0, stream,
                     idx, hist, p, inv);
  hipLaunchKernelGGL(main_kernel, dim3(N_SAMPLES / ROWS_PER_BLOCK), dim3(256),
                     0, stream, state, W, b, ls, eps, idx, p, inv,
                     out_action, out_lp);
}